// Round 22
// baseline (246.712 us; speedup 1.0000x reference)
//
#include <hip/hip_runtime.h>

// MetaPathGNN — only the edge2 (B->C) layer + output GEMM matter.
//
// R22 (on R19's 214us best): amortize B-fragment L2 traffic + widen gather MLP.
//  - k_fused: wave owns 64 rows (4 rt), block = 128 thr = 2 waves, grid 782.
//    Waves halve -> per-kernel B traffic halves (was 500MB L2 = the dominant
//    unreduced quantity; MFMA needs only ~5-9us).  96 MFMA per 16 B-loads
//    per chunk; 4 independent rt chains (2x ILP).  Epilogue+K3 per-16-row
//    tile from wave-private 8KB LDS slice; 16KB LDS/block; no barriers.
//  - k_gather: 8 edge slots x 8 lanes x 4 float4 -> 32 row-loads in flight
//    (was 8); reduce shfl_xor 8/16/32.  (R18 showed gather latency-bound.)
//  - B planes frag-order coalesced (R19), merged prep, 1-pass scan.
//
// ws (ints): [cnt N | fillc N | offs N | part 128 | tot 4 | srcw 2E |
//             wlh/wll/wch/wcl 16384u16 | woh/wol 8192u16 | bc 128f | buf N*128f]

#define HD 128
#define OD 64
#define SCAN_E 1024

typedef unsigned short u16;
typedef short v8s __attribute__((ext_vector_type(8)));
typedef float v4f __attribute__((ext_vector_type(4)));

union Frag {
    unsigned int u[4];
    uint4 q;
    v8s v;
};

__device__ __forceinline__ float softplus_f(float x) {
    return fmaxf(x, 0.0f) + log1pf(expf(-fabsf(x)));
}
__device__ __forceinline__ float sigmoid_f(float x) {
    return 1.0f / (1.0f + expf(-x));
}
// swizzled LDS offset within a [16][128] fp32 slice: granule XOR row&7
__device__ __forceinline__ int swz(int r, int c) {
    int g = (c >> 2) ^ (r & 7);
    return r * 128 + g * 4 + (c & 3);
}

__device__ __forceinline__ void split_store(float x, u16* ph, u16* pl) {
    unsigned int b = __float_as_uint(x);
    unsigned int h = b & 0xffff0000u;
    *ph = (u16)(h >> 16);
    float r = x - __uint_as_float(h);
    *pl = (u16)(__float_as_uint(r) >> 16);
}

// 8 floats -> 4 packed dwords hi, 4 packed dwords lo (2 bf16 per dword)
__device__ __forceinline__ void cvt_split8(const float* f, unsigned int* hi,
                                           unsigned int* lo) {
#pragma unroll
    for (int j = 0; j < 4; ++j) {
        unsigned int b0 = __float_as_uint(f[2 * j]);
        unsigned int b1 = __float_as_uint(f[2 * j + 1]);
        unsigned int h0 = b0 & 0xffff0000u;
        unsigned int h1 = b1 & 0xffff0000u;
        hi[j] = (h0 >> 16) | h1;
        float r0 = f[2 * j]     - __uint_as_float(h0);
        float r1 = f[2 * j + 1] - __uint_as_float(h1);
        lo[j] = (__float_as_uint(r0) >> 16) | (__float_as_uint(r1) & 0xffff0000u);
    }
}

// ---------------------------------------------------------------- prep: hist | wprep
// B planes in FRAG ORDER: element (k,n) -> u16 offset
//   K2 (128 cols): (((k>>5)*8 + (n>>4))*64 + ((k&31)>>3)*16 + (n&15))*8 + (k&7)
//   K3 ( 64 cols): (((k>>5)*4 + (n>>4))*64 + ((k&31)>>3)*16 + (n&15))*8 + (k&7)
__global__ __launch_bounds__(256) void k_prep(
    const int* __restrict__ edge, int* __restrict__ cnt, int E, int gE,
    const float* __restrict__ Wl, const float* __restrict__ W0,
    const float* __restrict__ W1, const float* __restrict__ Wout,
    const float* __restrict__ bl, const float* __restrict__ b0,
    const float* __restrict__ b1, const float* __restrict__ gatep,
    u16* __restrict__ wlh, u16* __restrict__ wll,
    u16* __restrict__ wch, u16* __restrict__ wcl,
    u16* __restrict__ woh, u16* __restrict__ wol, float* __restrict__ bc)
{
    if (blockIdx.x < (unsigned)gE) {
        int e = blockIdx.x * 256 + threadIdx.x;
        if (e < E) atomicAdd(cnt + edge[E + e], 1);
        return;
    }
    int i = (blockIdx.x - gE) * 256 + threadIdx.x;
    const float g = sigmoid_f(gatep[0]);
    if (i < 16384) {
        int n = i >> 7, k = i & 127;
        float a  = Wl[k * 128 + n];
        float w0 = W0[k * 128 + n];
        float w1 = W1[k * 128 + n];
        float c  = (1.f - g) * w0 + g * w1;
        int off = (((k >> 5) * 8 + (n >> 4)) * 64 +
                   ((k & 31) >> 3) * 16 + (n & 15)) * 8 + (k & 7);
        split_store(a, wlh + off, wll + off);
        split_store(c, wch + off, wcl + off);
    } else if (i < 24576) {
        int j = i - 16384;
        int n = j >> 7, k = j & 127;          // n 0..63, k 0..127
        float v = Wout[k * 64 + n];
        int off = (((k >> 5) * 4 + (n >> 4)) * 64 +
                   ((k & 31) >> 3) * 16 + (n & 15)) * 8 + (k & 7);
        split_store(v, woh + off, wol + off);
    } else if (i < 24704) {
        int t = i - 24576;
        bc[t] = bl[t] + (1.f - g) * b0[t] + g * b1[t];
    }
}

// ---------------------------------------------------------------- scan (1-pass, atomic base)
__global__ __launch_bounds__(256) void k_scan1(
    const int* __restrict__ cnt, int* __restrict__ offs,
    int* __restrict__ part, int* __restrict__ tot, int N)
{
    __shared__ int sh[256];
    const int t = threadIdx.x;
    const int base = blockIdx.x * SCAN_E + t * 4;
    int v[4], sum = 0;
#pragma unroll
    for (int i = 0; i < 4; ++i) {
        int idx = base + i;
        v[i] = (idx < N) ? cnt[idx] : 0;
        sum += v[i];
    }
    sh[t] = sum;
    __syncthreads();
    for (int off = 1; off < 256; off <<= 1) {
        int x = (t >= off) ? sh[t - off] : 0;
        __syncthreads();
        sh[t] += x;
        __syncthreads();
    }
    int run = (t > 0) ? sh[t - 1] : 0;
    if (t == 255) part[blockIdx.x] = atomicAdd(tot, sh[255]);
#pragma unroll
    for (int i = 0; i < 4; ++i) {
        int idx = base + i;
        if (idx < N) offs[idx] = run;
        run += v[i];
    }
}

// ---------------------------------------------------------------- CSR fill + weight
__global__ __launch_bounds__(256) void k_fillw(
    const int* __restrict__ edge, const float* __restrict__ tB,
    const float* __restrict__ tC, const float* __restrict__ lam_raw,
    const int* __restrict__ offs, const int* __restrict__ part,
    int* __restrict__ fillc, int2* __restrict__ srcw, int E)
{
    int e = blockIdx.x * 256 + threadIdx.x;
    if (e >= E) return;
    int s = edge[e];
    int d = edge[E + e];
    float lam = softplus_f(lam_raw[0]) + 1e-8f;
    float dt  = fmaxf(tC[d] - tB[s], 0.0f);
    float w   = expf(fmaxf(-lam * dt, -60.0f));
    int pos = offs[d] + part[d >> 10] + atomicAdd(fillc + d, 1);
    srcw[pos] = make_int2(s, __float_as_int(w));
}

// ---------------------------------------------------------------- gather
// wave per node; 8 edge slots x 8 lanes; lane owns cols l3*16..+15 (4 float4)
__global__ __launch_bounds__(256) void k_gather(
    const float* __restrict__ xB, const int2* __restrict__ srcw,
    const int* __restrict__ offs, const int* __restrict__ part,
    const int* __restrict__ cnt, float* __restrict__ aggn, int N)
{
    const int wave = (blockIdx.x * 256 + threadIdx.x) >> 6;
    const int lane = threadIdx.x & 63;
    const int slot = lane >> 3;        // 0..7
    const int l3   = lane & 7;         // col block: l3*16 .. +15
    if (wave >= N) return;
    const int r    = wave;
    const int degc = cnt[r];

    float* dstp = aggn + (size_t)r * HD + l3 * 16;
    if (degc == 0) {
        if (slot == 0) {
            float4 z = make_float4(0, 0, 0, 0);
#pragma unroll
            for (int c = 0; c < 4; ++c)
                *reinterpret_cast<float4*>(dstp + c * 4) = z;
        }
        return;
    }

    const int start = offs[r] + part[r >> 10];
    float4 a[4] = {make_float4(0, 0, 0, 0), make_float4(0, 0, 0, 0),
                   make_float4(0, 0, 0, 0), make_float4(0, 0, 0, 0)};
    float sw = 0.f;
    for (int j = slot; j < degc; j += 8) {
        int2 swp = srcw[start + j];
        float w = __int_as_float(swp.y);
        const float* row = xB + (size_t)swp.x * HD + l3 * 16;
#pragma unroll
        for (int c = 0; c < 4; ++c) {
            float4 x = *reinterpret_cast<const float4*>(row + c * 4);
            a[c].x = fmaf(w, x.x, a[c].x);
            a[c].y = fmaf(w, x.y, a[c].y);
            a[c].z = fmaf(w, x.z, a[c].z);
            a[c].w = fmaf(w, x.w, a[c].w);
        }
        sw += w;
    }
#pragma unroll
    for (int m = 8; m <= 32; m <<= 1) {
#pragma unroll
        for (int c = 0; c < 4; ++c) {
            a[c].x += __shfl_xor(a[c].x, m);
            a[c].y += __shfl_xor(a[c].y, m);
            a[c].z += __shfl_xor(a[c].z, m);
            a[c].w += __shfl_xor(a[c].w, m);
        }
        sw += __shfl_xor(sw, m);
    }
    float inv = 1.0f / fmaxf(sw, 1e-6f);
    if (slot == 0) {
#pragma unroll
        for (int c = 0; c < 4; ++c) {
            a[c].x *= inv; a[c].y *= inv; a[c].z *= inv; a[c].w *= inv;
            *reinterpret_cast<float4*>(dstp + c * 4) = a[c];
        }
    }
}

// ---------------------------------------------------------------- fused K2+K3
// block = 128 thr = 2 waves; wave owns 64 rows (4 rt x 16).  K2: acc[4][8]
// over K=256; A fp32 global->reg + split; B frag-order coalesced (shared
// across 4 rt -> half the per-kernel B traffic vs 32-row waves).
// Epilogue+K3 per-16-row tile from wave-private 8KB LDS slice.
__global__ __launch_bounds__(128) void k_fused(
    const float* __restrict__ xC, const float* __restrict__ aggn,
    const int* __restrict__ cnt,
    const u16* __restrict__ wlh, const u16* __restrict__ wll,
    const u16* __restrict__ wch, const u16* __restrict__ wcl,
    const u16* __restrict__ woh, const u16* __restrict__ wol,
    const float* __restrict__ bc, const float* __restrict__ lng,
    const float* __restrict__ lnb, const float* __restrict__ bout,
    float* __restrict__ out, int N)
{
    __shared__ float lds[2 * 16 * 128];     // 16 KB, per-wave 8KB slices

    const int lane = threadIdx.x & 63;
    const int wid  = threadIdx.x >> 6;      // 0..1
    const int lr   = lane & 15;             // frag row (A) / col (B/C)
    const int kb   = lane >> 4;             // k-block 0..3
    const int row0 = blockIdx.x * 128 + wid * 64;
    float* myl = lds + wid * 16 * 128;

    // ================= K2 =================
    v4f acc[4][8] = {};

#pragma unroll
    for (int mat = 0; mat < 2; ++mat) {
        const float* Asrc = mat ? xC : aggn;
        const uint4* BH = (const uint4*)(mat ? wch : wlh);
        const uint4* BL = (const uint4*)(mat ? wcl : wll);
#pragma unroll
        for (int kc = 0; kc < 4; ++kc) {
            Frag ah[4], al[4];
#pragma unroll
            for (int rt = 0; rt < 4; ++rt) {
                int r = row0 + rt * 16 + lr;
                r = (r < N) ? r : (N - 1);
                const float4* ap = (const float4*)(
                    Asrc + (size_t)r * HD + kc * 32 + kb * 8);
                float4 u0 = ap[0], u1 = ap[1];
                float f[8] = {u0.x, u0.y, u0.z, u0.w, u1.x, u1.y, u1.z, u1.w};
                cvt_split8(f, ah[rt].u, al[rt].u);
            }
#pragma unroll
            for (int ct = 0; ct < 8; ++ct) {
                int idx = (kc * 8 + ct) * 64 + lane;   // coalesced 1KB
                Frag bh, bl;
                bh.q = BH[idx];
                bl.q = BL[idx];
#pragma unroll
                for (int rt = 0; rt < 4; ++rt) {
                    acc[rt][ct] = __builtin_amdgcn_mfma_f32_16x16x32_bf16(
                        ah[rt].v, bh.v, acc[rt][ct], 0, 0, 0);
                    acc[rt][ct] = __builtin_amdgcn_mfma_f32_16x16x32_bf16(
                        ah[rt].v, bl.v, acc[rt][ct], 0, 0, 0);
                    acc[rt][ct] = __builtin_amdgcn_mfma_f32_16x16x32_bf16(
                        al[rt].v, bh.v, acc[rt][ct], 0, 0, 0);
                }
            }
        }
    }

    // ---- per-column constants
    float bcv[8], gav[8], bev[8];
#pragma unroll
    for (int ct = 0; ct < 8; ++ct) {
        int c = ct * 16 + lr;
        bcv[ct] = bc[c];
        gav[ct] = lng[c];
        bev[ct] = lnb[c];
    }
    float bov[4];
#pragma unroll
    for (int ct = 0; ct < 4; ++ct) bov[ct] = bout[ct * 16 + lr];

    const uint4* BH3 = (const uint4*)woh;
    const uint4* BL3 = (const uint4*)wol;

    // ======== per 16-row tile: epilogue -> slice -> K3 -> out ========
#pragma unroll
    for (int rt = 0; rt < 4; ++rt) {
        int rq = row0 + rt * 16 + kb * 4;    // first of this lane's 4 rows
        int cvr[4] = {0, 0, 0, 0};
        if (rq < N) {                        // N%4==0, rq%4==0 -> rq+3 < N
            int4 cv = *(const int4*)(cnt + rq);
            cvr[0] = cv.x; cvr[1] = cv.y; cvr[2] = cv.z; cvr[3] = cv.w;
        }
#pragma unroll
        for (int reg = 0; reg < 4; ++reg) {
            int rloc = kb * 4 + reg;         // 0..15 within the tile
            int r    = rq + reg;
            float yv[8];
            float s = 0.f, q = 0.f;
#pragma unroll
            for (int ct = 0; ct < 8; ++ct) {
                float v = acc[rt][ct][reg] + bcv[ct];
                v = fmaxf(v, 0.0f);
                yv[ct] = v;
                s += v;
                q += v * v;
            }
#pragma unroll
            for (int m = 1; m < 16; m <<= 1) {
                s += __shfl_xor(s, m);
                q += __shfl_xor(q, m);
            }
            float mu   = s * (1.0f / 128.0f);
            float var  = q * (1.0f / 128.0f) - mu * mu;
            float rstd = rsqrtf(var + 1e-5f);

            if (r < N) {
                if (cvr[reg] > 0) {
#pragma unroll
                    for (int ct = 0; ct < 8; ++ct)
                        myl[swz(rloc, ct * 16 + lr)] =
                            (yv[ct] - mu) * rstd * gav[ct] + bev[ct];
                } else {
                    size_t base = (size_t)r * HD;
#pragma unroll
                    for (int ct = 0; ct < 8; ++ct)
                        myl[swz(rloc, ct * 16 + lr)] = xC[base + ct * 16 + lr];
                }
            } else {
#pragma unroll
                for (int ct = 0; ct < 8; ++ct)
                    myl[swz(rloc, ct * 16 + lr)] = 0.0f;
            }
        }
        // wave-private slice; same-wave DS ordering is in-order

        // ---- K3 on this 16-row tile
        v4f acc2[4] = {};
#pragma unroll
        for (int kc = 0; kc < 4; ++kc) {
            Frag ah, al;
            {
                int c0 = kc * 32 + kb * 8;
                float4 u0 = *reinterpret_cast<const float4*>(&myl[swz(lr, c0)]);
                float4 u1 = *reinterpret_cast<const float4*>(&myl[swz(lr, c0 + 4)]);
                float f[8] = {u0.x, u0.y, u0.z, u0.w, u1.x, u1.y, u1.z, u1.w};
                cvt_split8(f, ah.u, al.u);
            }
#pragma unroll
            for (int ct = 0; ct < 4; ++ct) {
                int idx = (kc * 4 + ct) * 64 + lane;   // coalesced 1KB
                Frag bh, bl;
                bh.q = BH3[idx];
                bl.q = BL3[idx];
                acc2[ct] = __builtin_amdgcn_mfma_f32_16x16x32_bf16(
                    ah.v, bh.v, acc2[ct], 0, 0, 0);
                acc2[ct] = __builtin_amdgcn_mfma_f32_16x16x32_bf16(
                    ah.v, bl.v, acc2[ct], 0, 0, 0);
                acc2[ct] = __builtin_amdgcn_mfma_f32_16x16x32_bf16(
                    al.v, bh.v, acc2[ct], 0, 0, 0);
            }
        }

#pragma unroll
        for (int reg = 0; reg < 4; ++reg) {
            int r = rq + reg;
            if (r < N) {
#pragma unroll
                for (int ct = 0; ct < 4; ++ct)
                    out[(size_t)r * OD + ct * 16 + lr] = acc2[ct][reg] + bov[ct];
            }
        }
    }
}

// ---------------------------------------------------------------- launch
extern "C" void kernel_launch(void* const* d_in, const int* in_sizes, int n_in,
                              void* d_out, int out_size, void* d_ws, size_t ws_size,
                              hipStream_t stream) {
    const float* xB    = (const float*)d_in[1];
    const float* xC    = (const float*)d_in[2];
    const float* tB    = (const float*)d_in[4];
    const float* tC    = (const float*)d_in[5];
    const int*   edge2 = (const int*)d_in[7];
    const float* Wl1   = (const float*)d_in[18];
    const float* bl1   = (const float*)d_in[19];
    const float* W01   = (const float*)d_in[20];
    const float* b01   = (const float*)d_in[21];
    const float* W11   = (const float*)d_in[22];
    const float* b11   = (const float*)d_in[23];
    const float* gate1 = (const float*)d_in[24];
    const float* lam1  = (const float*)d_in[25];
    const float* lng1  = (const float*)d_in[26];
    const float* lnb1  = (const float*)d_in[27];
    const float* Wout  = (const float*)d_in[28];
    const float* bout  = (const float*)d_in[29];

    const int N = in_sizes[2] / HD;
    const int E = in_sizes[7] / 2;

    int*   cnt   = (int*)d_ws;
    int*   fillc = cnt + N;
    int*   offs  = fillc + N;
    int*   part  = offs + N;
    int*   tot   = part + 128;
    int2*  srcw  = (int2*)(tot + 4);
    u16*   wlh   = (u16*)(srcw + E);
    u16*   wll   = wlh + 16384;
    u16*   wch   = wll + 16384;
    u16*   wcl   = wch + 16384;
    u16*   woh   = wcl + 16384;
    u16*   wol   = woh + 8192;
    float* bc    = (float*)(wol + 8192);
    float* buf   = bc + 128;             // agg_norm fp32

    hipMemsetAsync(cnt, 0, (size_t)2 * N * sizeof(int), stream);
    hipMemsetAsync(tot, 0, sizeof(int), stream);

    dim3 blk(256);
    const int gE = (E + 255) / 256;
    const int NB = (N + SCAN_E - 1) / SCAN_E;

    k_prep <<<gE + 97, blk, 0, stream>>>(edge2, cnt, E, gE,
                                         Wl1, W01, W11, Wout, bl1, b01, b11,
                                         gate1, wlh, wll, wch, wcl, woh, wol, bc);
    k_scan1<<<NB, blk, 0, stream>>>(cnt, offs, part, tot, N);
    k_fillw<<<gE, blk, 0, stream>>>(edge2, tB, tC, lam1, offs, part, fillc, srcw, E);

    const int gN64 = (N * 64 + 255) / 256;
    k_gather<<<gN64, blk, 0, stream>>>(xB, srcw, offs, part, cnt, buf, N);

    const int GB = (N + 127) / 128;
    k_fused<<<GB, dim3(128), 0, stream>>>(xC, buf, cnt,
                                          wlh, wll, wch, wcl, woh, wol,
                                          bc, lng1, lnb1, bout, (float*)d_out, N);
}

// Round 23
// 226.566 us; speedup vs baseline: 1.0889x; 1.0889x over previous
//
#include <hip/hip_runtime.h>

// MetaPathGNN — only the edge2 (B->C) layer + output GEMM matter.
//
// R23 (on R19's 214us best): k_fused -> 512-thr blocks (8 waves x 32 rows),
// per-wave LDS slice 8KB (epilogue+K3 per-16-row tile, wave-private, no
// barriers).  LDS/block stays 64KB but waves/CU cap doubles 8 -> 16.
// R22 falsified the B-traffic theory (halving B hurt via occupancy); the
// consistent 13-variant diagnosis is per-wave load-latency x 1/waves-resident.
// Everything else identical to R19 (best measured): fp32 A + in-reg split,
// frag-order coalesced B planes, R10 gather, merged prep, 1-pass scan.
//
// ws (ints): [cnt N | fillc N | offs N | part 128 | tot 4 | srcw 2E |
//             wlh/wll/wch/wcl 16384u16 | woh/wol 8192u16 | bc 128f | buf N*128f]

#define HD 128
#define OD 64
#define SCAN_E 1024

typedef unsigned short u16;
typedef short v8s __attribute__((ext_vector_type(8)));
typedef float v4f __attribute__((ext_vector_type(4)));

union Frag {
    unsigned int u[4];
    uint4 q;
    v8s v;
};

__device__ __forceinline__ float softplus_f(float x) {
    return fmaxf(x, 0.0f) + log1pf(expf(-fabsf(x)));
}
__device__ __forceinline__ float sigmoid_f(float x) {
    return 1.0f / (1.0f + expf(-x));
}
// swizzled LDS offset within a [16][128] fp32 slice: granule XOR row&7
__device__ __forceinline__ int swz(int r, int c) {
    int g = (c >> 2) ^ (r & 7);
    return r * 128 + g * 4 + (c & 3);
}

__device__ __forceinline__ void split_store(float x, u16* ph, u16* pl) {
    unsigned int b = __float_as_uint(x);
    unsigned int h = b & 0xffff0000u;
    *ph = (u16)(h >> 16);
    float r = x - __uint_as_float(h);
    *pl = (u16)(__float_as_uint(r) >> 16);
}

// 8 floats -> 4 packed dwords hi, 4 packed dwords lo (2 bf16 per dword)
__device__ __forceinline__ void cvt_split8(const float* f, unsigned int* hi,
                                           unsigned int* lo) {
#pragma unroll
    for (int j = 0; j < 4; ++j) {
        unsigned int b0 = __float_as_uint(f[2 * j]);
        unsigned int b1 = __float_as_uint(f[2 * j + 1]);
        unsigned int h0 = b0 & 0xffff0000u;
        unsigned int h1 = b1 & 0xffff0000u;
        hi[j] = (h0 >> 16) | h1;
        float r0 = f[2 * j]     - __uint_as_float(h0);
        float r1 = f[2 * j + 1] - __uint_as_float(h1);
        lo[j] = (__float_as_uint(r0) >> 16) | (__float_as_uint(r1) & 0xffff0000u);
    }
}

// ---------------------------------------------------------------- prep: hist | wprep
// B planes in FRAG ORDER: element (k,n) -> u16 offset
//   K2 (128 cols): (((k>>5)*8 + (n>>4))*64 + ((k&31)>>3)*16 + (n&15))*8 + (k&7)
//   K3 ( 64 cols): (((k>>5)*4 + (n>>4))*64 + ((k&31)>>3)*16 + (n&15))*8 + (k&7)
__global__ __launch_bounds__(256) void k_prep(
    const int* __restrict__ edge, int* __restrict__ cnt, int E, int gE,
    const float* __restrict__ Wl, const float* __restrict__ W0,
    const float* __restrict__ W1, const float* __restrict__ Wout,
    const float* __restrict__ bl, const float* __restrict__ b0,
    const float* __restrict__ b1, const float* __restrict__ gatep,
    u16* __restrict__ wlh, u16* __restrict__ wll,
    u16* __restrict__ wch, u16* __restrict__ wcl,
    u16* __restrict__ woh, u16* __restrict__ wol, float* __restrict__ bc)
{
    if (blockIdx.x < (unsigned)gE) {
        int e = blockIdx.x * 256 + threadIdx.x;
        if (e < E) atomicAdd(cnt + edge[E + e], 1);
        return;
    }
    int i = (blockIdx.x - gE) * 256 + threadIdx.x;
    const float g = sigmoid_f(gatep[0]);
    if (i < 16384) {
        int n = i >> 7, k = i & 127;
        float a  = Wl[k * 128 + n];
        float w0 = W0[k * 128 + n];
        float w1 = W1[k * 128 + n];
        float c  = (1.f - g) * w0 + g * w1;
        int off = (((k >> 5) * 8 + (n >> 4)) * 64 +
                   ((k & 31) >> 3) * 16 + (n & 15)) * 8 + (k & 7);
        split_store(a, wlh + off, wll + off);
        split_store(c, wch + off, wcl + off);
    } else if (i < 24576) {
        int j = i - 16384;
        int n = j >> 7, k = j & 127;          // n 0..63, k 0..127
        float v = Wout[k * 64 + n];
        int off = (((k >> 5) * 4 + (n >> 4)) * 64 +
                   ((k & 31) >> 3) * 16 + (n & 15)) * 8 + (k & 7);
        split_store(v, woh + off, wol + off);
    } else if (i < 24704) {
        int t = i - 24576;
        bc[t] = bl[t] + (1.f - g) * b0[t] + g * b1[t];
    }
}

// ---------------------------------------------------------------- scan (1-pass, atomic base)
__global__ __launch_bounds__(256) void k_scan1(
    const int* __restrict__ cnt, int* __restrict__ offs,
    int* __restrict__ part, int* __restrict__ tot, int N)
{
    __shared__ int sh[256];
    const int t = threadIdx.x;
    const int base = blockIdx.x * SCAN_E + t * 4;
    int v[4], sum = 0;
#pragma unroll
    for (int i = 0; i < 4; ++i) {
        int idx = base + i;
        v[i] = (idx < N) ? cnt[idx] : 0;
        sum += v[i];
    }
    sh[t] = sum;
    __syncthreads();
    for (int off = 1; off < 256; off <<= 1) {
        int x = (t >= off) ? sh[t - off] : 0;
        __syncthreads();
        sh[t] += x;
        __syncthreads();
    }
    int run = (t > 0) ? sh[t - 1] : 0;
    if (t == 255) part[blockIdx.x] = atomicAdd(tot, sh[255]);
#pragma unroll
    for (int i = 0; i < 4; ++i) {
        int idx = base + i;
        if (idx < N) offs[idx] = run;
        run += v[i];
    }
}

// ---------------------------------------------------------------- CSR fill + weight
__global__ __launch_bounds__(256) void k_fillw(
    const int* __restrict__ edge, const float* __restrict__ tB,
    const float* __restrict__ tC, const float* __restrict__ lam_raw,
    const int* __restrict__ offs, const int* __restrict__ part,
    int* __restrict__ fillc, int2* __restrict__ srcw, int E)
{
    int e = blockIdx.x * 256 + threadIdx.x;
    if (e >= E) return;
    int s = edge[e];
    int d = edge[E + e];
    float lam = softplus_f(lam_raw[0]) + 1e-8f;
    float dt  = fmaxf(tC[d] - tB[s], 0.0f);
    float w   = expf(fmaxf(-lam * dt, -60.0f));
    int pos = offs[d] + part[d >> 10] + atomicAdd(fillc + d, 1);
    srcw[pos] = make_int2(s, __float_as_int(w));
}

// ---------------------------------------------------------------- gather
// wave per node; 4 edge slots x 16 lanes; lane covers cols [l4*4) and [64+l4*4)
__global__ __launch_bounds__(256) void k_gather(
    const float* __restrict__ xB, const int2* __restrict__ srcw,
    const int* __restrict__ offs, const int* __restrict__ part,
    const int* __restrict__ cnt, float* __restrict__ aggn, int N)
{
    const int wave = (blockIdx.x * 256 + threadIdx.x) >> 6;
    const int lane = threadIdx.x & 63;
    const int slot = lane >> 4;
    const int l4   = lane & 15;
    if (wave >= N) return;
    const int r    = wave;
    const int degc = cnt[r];

    float* dstp = aggn + (size_t)r * HD;
    if (degc == 0) {
        if (slot == 0) {
            *reinterpret_cast<float4*>(dstp + l4 * 4) = make_float4(0, 0, 0, 0);
            *reinterpret_cast<float4*>(dstp + 64 + l4 * 4) = make_float4(0, 0, 0, 0);
        }
        return;
    }

    const int start = offs[r] + part[r >> 10];
    float4 a0 = make_float4(0, 0, 0, 0), a1 = make_float4(0, 0, 0, 0);
    float sw = 0.f;
#pragma unroll 2
    for (int j = slot; j < degc; j += 4) {
        int2 swp = srcw[start + j];
        float w = __int_as_float(swp.y);
        const float* row = xB + (size_t)swp.x * HD;
        float4 x0 = *reinterpret_cast<const float4*>(row + l4 * 4);
        float4 x1 = *reinterpret_cast<const float4*>(row + 64 + l4 * 4);
        a0.x = fmaf(w, x0.x, a0.x); a0.y = fmaf(w, x0.y, a0.y);
        a0.z = fmaf(w, x0.z, a0.z); a0.w = fmaf(w, x0.w, a0.w);
        a1.x = fmaf(w, x1.x, a1.x); a1.y = fmaf(w, x1.y, a1.y);
        a1.z = fmaf(w, x1.z, a1.z); a1.w = fmaf(w, x1.w, a1.w);
        sw += w;
    }
#pragma unroll
    for (int m = 16; m <= 32; m <<= 1) {
        a0.x += __shfl_xor(a0.x, m); a0.y += __shfl_xor(a0.y, m);
        a0.z += __shfl_xor(a0.z, m); a0.w += __shfl_xor(a0.w, m);
        a1.x += __shfl_xor(a1.x, m); a1.y += __shfl_xor(a1.y, m);
        a1.z += __shfl_xor(a1.z, m); a1.w += __shfl_xor(a1.w, m);
        sw   += __shfl_xor(sw, m);
    }
    float inv = 1.0f / fmaxf(sw, 1e-6f);
    if (slot == 0) {
        a0.x *= inv; a0.y *= inv; a0.z *= inv; a0.w *= inv;
        a1.x *= inv; a1.y *= inv; a1.z *= inv; a1.w *= inv;
        *reinterpret_cast<float4*>(dstp + l4 * 4) = a0;
        *reinterpret_cast<float4*>(dstp + 64 + l4 * 4) = a1;
    }
}

// ---------------------------------------------------------------- fused K2+K3
// block = 512 thr = 8 waves; wave owns 32 rows (R19 structure).  LDS: 8
// wave-private 8KB slices (64KB/block -> 2 blocks = 16 waves/CU possible).
// K2: acc[2][8] over K=256; A fp32 global->reg + split; B frag-order 1KB.
// Epilogue+K3 per-16-row tile from the slice; no barriers.
__global__ __launch_bounds__(512) void k_fused(
    const float* __restrict__ xC, const float* __restrict__ aggn,
    const int* __restrict__ cnt,
    const u16* __restrict__ wlh, const u16* __restrict__ wll,
    const u16* __restrict__ wch, const u16* __restrict__ wcl,
    const u16* __restrict__ woh, const u16* __restrict__ wol,
    const float* __restrict__ bc, const float* __restrict__ lng,
    const float* __restrict__ lnb, const float* __restrict__ bout,
    float* __restrict__ out, int N)
{
    __shared__ float lds[8 * 16 * 128];     // 64 KB, per-wave 8KB slices

    const int lane = threadIdx.x & 63;
    const int wid  = threadIdx.x >> 6;      // 0..7
    const int lr   = lane & 15;             // frag row (A) / col (B/C)
    const int kb   = lane >> 4;             // k-block 0..3
    const int row0 = blockIdx.x * 256 + wid * 32;
    float* myl = lds + wid * 16 * 128;

    // ================= K2 =================
    v4f acc[2][8] = {};

#pragma unroll
    for (int mat = 0; mat < 2; ++mat) {
        const float* Asrc = mat ? xC : aggn;
        const uint4* BH = (const uint4*)(mat ? wch : wlh);
        const uint4* BL = (const uint4*)(mat ? wcl : wll);
#pragma unroll
        for (int kc = 0; kc < 4; ++kc) {
            Frag ah[2], al[2];
#pragma unroll
            for (int rt = 0; rt < 2; ++rt) {
                int r = row0 + rt * 16 + lr;
                r = (r < N) ? r : (N - 1);
                const float4* ap = (const float4*)(
                    Asrc + (size_t)r * HD + kc * 32 + kb * 8);
                float4 u0 = ap[0], u1 = ap[1];
                float f[8] = {u0.x, u0.y, u0.z, u0.w, u1.x, u1.y, u1.z, u1.w};
                cvt_split8(f, ah[rt].u, al[rt].u);
            }
#pragma unroll
            for (int ct = 0; ct < 8; ++ct) {
                int idx = (kc * 8 + ct) * 64 + lane;   // coalesced 1KB
                Frag bh, bl;
                bh.q = BH[idx];
                bl.q = BL[idx];
#pragma unroll
                for (int rt = 0; rt < 2; ++rt) {
                    acc[rt][ct] = __builtin_amdgcn_mfma_f32_16x16x32_bf16(
                        ah[rt].v, bh.v, acc[rt][ct], 0, 0, 0);
                    acc[rt][ct] = __builtin_amdgcn_mfma_f32_16x16x32_bf16(
                        ah[rt].v, bl.v, acc[rt][ct], 0, 0, 0);
                    acc[rt][ct] = __builtin_amdgcn_mfma_f32_16x16x32_bf16(
                        al[rt].v, bh.v, acc[rt][ct], 0, 0, 0);
                }
            }
        }
    }

    // ---- per-column constants
    float bcv[8], gav[8], bev[8];
#pragma unroll
    for (int ct = 0; ct < 8; ++ct) {
        int c = ct * 16 + lr;
        bcv[ct] = bc[c];
        gav[ct] = lng[c];
        bev[ct] = lnb[c];
    }
    float bov[4];
#pragma unroll
    for (int ct = 0; ct < 4; ++ct) bov[ct] = bout[ct * 16 + lr];

    const uint4* BH3 = (const uint4*)woh;
    const uint4* BL3 = (const uint4*)wol;

    // ======== per 16-row tile: epilogue -> slice -> K3 -> out ========
#pragma unroll
    for (int rt = 0; rt < 2; ++rt) {
        int rq = row0 + rt * 16 + kb * 4;    // first of this lane's 4 rows
        int cvr[4] = {0, 0, 0, 0};
        if (rq < N) {                        // N%4==0, rq%4==0 -> rq+3 < N
            int4 cv = *(const int4*)(cnt + rq);
            cvr[0] = cv.x; cvr[1] = cv.y; cvr[2] = cv.z; cvr[3] = cv.w;
        }
#pragma unroll
        for (int reg = 0; reg < 4; ++reg) {
            int rloc = kb * 4 + reg;         // 0..15 within the tile
            int r    = rq + reg;
            float yv[8];
            float s = 0.f, q = 0.f;
#pragma unroll
            for (int ct = 0; ct < 8; ++ct) {
                float v = acc[rt][ct][reg] + bcv[ct];
                v = fmaxf(v, 0.0f);
                yv[ct] = v;
                s += v;
                q += v * v;
            }
#pragma unroll
            for (int m = 1; m < 16; m <<= 1) {
                s += __shfl_xor(s, m);
                q += __shfl_xor(q, m);
            }
            float mu   = s * (1.0f / 128.0f);
            float var  = q * (1.0f / 128.0f) - mu * mu;
            float rstd = rsqrtf(var + 1e-5f);

            if (r < N) {
                if (cvr[reg] > 0) {
#pragma unroll
                    for (int ct = 0; ct < 8; ++ct)
                        myl[swz(rloc, ct * 16 + lr)] =
                            (yv[ct] - mu) * rstd * gav[ct] + bev[ct];
                } else {
                    size_t base = (size_t)r * HD;
#pragma unroll
                    for (int ct = 0; ct < 8; ++ct)
                        myl[swz(rloc, ct * 16 + lr)] = xC[base + ct * 16 + lr];
                }
            } else {
#pragma unroll
                for (int ct = 0; ct < 8; ++ct)
                    myl[swz(rloc, ct * 16 + lr)] = 0.0f;
            }
        }
        // wave-private slice; same-wave DS ordering is in-order

        // ---- K3 on this 16-row tile
        v4f acc2[4] = {};
#pragma unroll
        for (int kc = 0; kc < 4; ++kc) {
            Frag ah, al;
            {
                int c0 = kc * 32 + kb * 8;
                float4 u0 = *reinterpret_cast<const float4*>(&myl[swz(lr, c0)]);
                float4 u1 = *reinterpret_cast<const float4*>(&myl[swz(lr, c0 + 4)]);
                float f[8] = {u0.x, u0.y, u0.z, u0.w, u1.x, u1.y, u1.z, u1.w};
                cvt_split8(f, ah.u, al.u);
            }
#pragma unroll
            for (int ct = 0; ct < 4; ++ct) {
                int idx = (kc * 4 + ct) * 64 + lane;   // coalesced 1KB
                Frag bh, bl;
                bh.q = BH3[idx];
                bl.q = BL3[idx];
                acc2[ct] = __builtin_amdgcn_mfma_f32_16x16x32_bf16(
                    ah.v, bh.v, acc2[ct], 0, 0, 0);
                acc2[ct] = __builtin_amdgcn_mfma_f32_16x16x32_bf16(
                    ah.v, bl.v, acc2[ct], 0, 0, 0);
                acc2[ct] = __builtin_amdgcn_mfma_f32_16x16x32_bf16(
                    al.v, bh.v, acc2[ct], 0, 0, 0);
            }
        }

#pragma unroll
        for (int reg = 0; reg < 4; ++reg) {
            int r = rq + reg;
            if (r < N) {
#pragma unroll
                for (int ct = 0; ct < 4; ++ct)
                    out[(size_t)r * OD + ct * 16 + lr] = acc2[ct][reg] + bov[ct];
            }
        }
    }
}

// ---------------------------------------------------------------- launch
extern "C" void kernel_launch(void* const* d_in, const int* in_sizes, int n_in,
                              void* d_out, int out_size, void* d_ws, size_t ws_size,
                              hipStream_t stream) {
    const float* xB    = (const float*)d_in[1];
    const float* xC    = (const float*)d_in[2];
    const float* tB    = (const float*)d_in[4];
    const float* tC    = (const float*)d_in[5];
    const int*   edge2 = (const int*)d_in[7];
    const float* Wl1   = (const float*)d_in[18];
    const float* bl1   = (const float*)d_in[19];
    const float* W01   = (const float*)d_in[20];
    const float* b01   = (const float*)d_in[21];
    const float* W11   = (const float*)d_in[22];
    const float* b11   = (const float*)d_in[23];
    const float* gate1 = (const float*)d_in[24];
    const float* lam1  = (const float*)d_in[25];
    const float* lng1  = (const float*)d_in[26];
    const float* lnb1  = (const float*)d_in[27];
    const float* Wout  = (const float*)d_in[28];
    const float* bout  = (const float*)d_in[29];

    const int N = in_sizes[2] / HD;
    const int E = in_sizes[7] / 2;

    int*   cnt   = (int*)d_ws;
    int*   fillc = cnt + N;
    int*   offs  = fillc + N;
    int*   part  = offs + N;
    int*   tot   = part + 128;
    int2*  srcw  = (int2*)(tot + 4);
    u16*   wlh   = (u16*)(srcw + E);
    u16*   wll   = wlh + 16384;
    u16*   wch   = wll + 16384;
    u16*   wcl   = wch + 16384;
    u16*   woh   = wcl + 16384;
    u16*   wol   = woh + 8192;
    float* bc    = (float*)(wol + 8192);
    float* buf   = bc + 128;             // agg_norm fp32

    hipMemsetAsync(cnt, 0, (size_t)2 * N * sizeof(int), stream);
    hipMemsetAsync(tot, 0, sizeof(int), stream);

    dim3 blk(256);
    const int gE = (E + 255) / 256;
    const int NB = (N + SCAN_E - 1) / SCAN_E;

    k_prep <<<gE + 97, blk, 0, stream>>>(edge2, cnt, E, gE,
                                         Wl1, W01, W11, Wout, bl1, b01, b11,
                                         gate1, wlh, wll, wch, wcl, woh, wol, bc);
    k_scan1<<<NB, blk, 0, stream>>>(cnt, offs, part, tot, N);
    k_fillw<<<gE, blk, 0, stream>>>(edge2, tB, tC, lam1, offs, part, fillc, srcw, E);

    const int gN64 = (N * 64 + 255) / 256;
    k_gather<<<gN64, blk, 0, stream>>>(xB, srcw, offs, part, cnt, buf, N);

    const int GB = (N + 255) / 256;
    k_fused<<<GB, dim3(512), 0, stream>>>(xC, buf, cnt,
                                          wlh, wll, wch, wcl, woh, wol,
                                          bc, lng1, lnb1, bout, (float*)d_out, N);
}

// Round 24
// 219.223 us; speedup vs baseline: 1.1254x; 1.0335x over previous
//
#include <hip/hip_runtime.h>

// MetaPathGNN — only the edge2 (B->C) layer + output GEMM matter.
//
// R24 = exact revert to R19 (session best, 214.0us measured in R21).
// 14 structural variants of k_fused (VGPR 88-200, LDS 16-64KB, blocks
// 128-512 thr, reg/LDS/async A-staging, scattered/coalesced/LDS-shared B,
// 16/32/64 rows/wave) all land at 79-104us with identical idle-pipe
// counters -> dependent-load-latency plateau; this config is the minimum.
//  - R10 fused core: A fp32 global->reg + in-reg bf16 split.
//  - Frag-order coalesced B planes (1KB loads).
//  - R10 gather (4 edge slots x 16 lanes, no edge-skip).
//  - merged prep (hist|wprep one grid), single-pass scan (atomic base).
//
// ws (ints): [cnt N | fillc N | offs N | part 128 | tot 4 | srcw 2E |
//             wlh/wll/wch/wcl 16384u16 | woh/wol 8192u16 | bc 128f | buf N*128f]

#define HD 128
#define OD 64
#define SCAN_E 1024

typedef unsigned short u16;
typedef short v8s __attribute__((ext_vector_type(8)));
typedef float v4f __attribute__((ext_vector_type(4)));

union Frag {
    unsigned int u[4];
    uint4 q;
    v8s v;
};

__device__ __forceinline__ float softplus_f(float x) {
    return fmaxf(x, 0.0f) + log1pf(expf(-fabsf(x)));
}
__device__ __forceinline__ float sigmoid_f(float x) {
    return 1.0f / (1.0f + expf(-x));
}
// swizzled LDS offset within a [32][128] fp32 slice: granule XOR row&7
__device__ __forceinline__ int swz(int r, int c) {
    int g = (c >> 2) ^ (r & 7);
    return r * 128 + g * 4 + (c & 3);
}

// split x into bf16 hi + bf16 lo (truncation split; residual ~2^-17 |x|)
__device__ __forceinline__ void split_store(float x, u16* ph, u16* pl) {
    unsigned int b = __float_as_uint(x);
    unsigned int h = b & 0xffff0000u;
    *ph = (u16)(h >> 16);
    float r = x - __uint_as_float(h);
    *pl = (u16)(__float_as_uint(r) >> 16);
}

// 8 floats -> 4 packed dwords hi, 4 packed dwords lo (2 bf16 per dword)
__device__ __forceinline__ void cvt_split8(const float* f, unsigned int* hi,
                                           unsigned int* lo) {
#pragma unroll
    for (int j = 0; j < 4; ++j) {
        unsigned int b0 = __float_as_uint(f[2 * j]);
        unsigned int b1 = __float_as_uint(f[2 * j + 1]);
        unsigned int h0 = b0 & 0xffff0000u;
        unsigned int h1 = b1 & 0xffff0000u;
        hi[j] = (h0 >> 16) | h1;
        float r0 = f[2 * j]     - __uint_as_float(h0);
        float r1 = f[2 * j + 1] - __uint_as_float(h1);
        lo[j] = (__float_as_uint(r0) >> 16) | (__float_as_uint(r1) & 0xffff0000u);
    }
}

// ---------------------------------------------------------------- prep: hist | wprep
// B planes in FRAG ORDER: element (k,n) -> u16 offset
//   K2 (128 cols): (((k>>5)*8 + (n>>4))*64 + ((k&31)>>3)*16 + (n&15))*8 + (k&7)
//   K3 ( 64 cols): (((k>>5)*4 + (n>>4))*64 + ((k&31)>>3)*16 + (n&15))*8 + (k&7)
__global__ __launch_bounds__(256) void k_prep(
    const int* __restrict__ edge, int* __restrict__ cnt, int E, int gE,
    const float* __restrict__ Wl, const float* __restrict__ W0,
    const float* __restrict__ W1, const float* __restrict__ Wout,
    const float* __restrict__ bl, const float* __restrict__ b0,
    const float* __restrict__ b1, const float* __restrict__ gatep,
    u16* __restrict__ wlh, u16* __restrict__ wll,
    u16* __restrict__ wch, u16* __restrict__ wcl,
    u16* __restrict__ woh, u16* __restrict__ wol, float* __restrict__ bc)
{
    if (blockIdx.x < (unsigned)gE) {
        int e = blockIdx.x * 256 + threadIdx.x;
        if (e < E) atomicAdd(cnt + edge[E + e], 1);
        return;
    }
    int i = (blockIdx.x - gE) * 256 + threadIdx.x;
    const float g = sigmoid_f(gatep[0]);
    if (i < 16384) {
        int n = i >> 7, k = i & 127;
        float a  = Wl[k * 128 + n];
        float w0 = W0[k * 128 + n];
        float w1 = W1[k * 128 + n];
        float c  = (1.f - g) * w0 + g * w1;
        int off = (((k >> 5) * 8 + (n >> 4)) * 64 +
                   ((k & 31) >> 3) * 16 + (n & 15)) * 8 + (k & 7);
        split_store(a, wlh + off, wll + off);
        split_store(c, wch + off, wcl + off);
    } else if (i < 24576) {
        int j = i - 16384;
        int n = j >> 7, k = j & 127;          // n 0..63, k 0..127
        float v = Wout[k * 64 + n];
        int off = (((k >> 5) * 4 + (n >> 4)) * 64 +
                   ((k & 31) >> 3) * 16 + (n & 15)) * 8 + (k & 7);
        split_store(v, woh + off, wol + off);
    } else if (i < 24704) {
        int t = i - 24576;
        bc[t] = bl[t] + (1.f - g) * b0[t] + g * b1[t];
    }
}

// ---------------------------------------------------------------- scan (1-pass, atomic base)
__global__ __launch_bounds__(256) void k_scan1(
    const int* __restrict__ cnt, int* __restrict__ offs,
    int* __restrict__ part, int* __restrict__ tot, int N)
{
    __shared__ int sh[256];
    const int t = threadIdx.x;
    const int base = blockIdx.x * SCAN_E + t * 4;
    int v[4], sum = 0;
#pragma unroll
    for (int i = 0; i < 4; ++i) {
        int idx = base + i;
        v[i] = (idx < N) ? cnt[idx] : 0;
        sum += v[i];
    }
    sh[t] = sum;
    __syncthreads();
    for (int off = 1; off < 256; off <<= 1) {
        int x = (t >= off) ? sh[t - off] : 0;
        __syncthreads();
        sh[t] += x;
        __syncthreads();
    }
    int run = (t > 0) ? sh[t - 1] : 0;
    if (t == 255) part[blockIdx.x] = atomicAdd(tot, sh[255]);
#pragma unroll
    for (int i = 0; i < 4; ++i) {
        int idx = base + i;
        if (idx < N) offs[idx] = run;
        run += v[i];
    }
}

// ---------------------------------------------------------------- CSR fill + weight
__global__ __launch_bounds__(256) void k_fillw(
    const int* __restrict__ edge, const float* __restrict__ tB,
    const float* __restrict__ tC, const float* __restrict__ lam_raw,
    const int* __restrict__ offs, const int* __restrict__ part,
    int* __restrict__ fillc, int2* __restrict__ srcw, int E)
{
    int e = blockIdx.x * 256 + threadIdx.x;
    if (e >= E) return;
    int s = edge[e];
    int d = edge[E + e];
    float lam = softplus_f(lam_raw[0]) + 1e-8f;
    float dt  = fmaxf(tC[d] - tB[s], 0.0f);
    float w   = expf(fmaxf(-lam * dt, -60.0f));
    int pos = offs[d] + part[d >> 10] + atomicAdd(fillc + d, 1);
    srcw[pos] = make_int2(s, __float_as_int(w));
}

// ---------------------------------------------------------------- gather
// wave per node; 4 edge slots x 16 lanes; lane covers cols [l4*4) and [64+l4*4)
__global__ __launch_bounds__(256) void k_gather(
    const float* __restrict__ xB, const int2* __restrict__ srcw,
    const int* __restrict__ offs, const int* __restrict__ part,
    const int* __restrict__ cnt, float* __restrict__ aggn, int N)
{
    const int wave = (blockIdx.x * 256 + threadIdx.x) >> 6;
    const int lane = threadIdx.x & 63;
    const int slot = lane >> 4;
    const int l4   = lane & 15;
    if (wave >= N) return;
    const int r    = wave;
    const int degc = cnt[r];

    float* dstp = aggn + (size_t)r * HD;
    if (degc == 0) {
        if (slot == 0) {
            *reinterpret_cast<float4*>(dstp + l4 * 4) = make_float4(0, 0, 0, 0);
            *reinterpret_cast<float4*>(dstp + 64 + l4 * 4) = make_float4(0, 0, 0, 0);
        }
        return;
    }

    const int start = offs[r] + part[r >> 10];
    float4 a0 = make_float4(0, 0, 0, 0), a1 = make_float4(0, 0, 0, 0);
    float sw = 0.f;
#pragma unroll 2
    for (int j = slot; j < degc; j += 4) {
        int2 swp = srcw[start + j];
        float w = __int_as_float(swp.y);
        const float* row = xB + (size_t)swp.x * HD;
        float4 x0 = *reinterpret_cast<const float4*>(row + l4 * 4);
        float4 x1 = *reinterpret_cast<const float4*>(row + 64 + l4 * 4);
        a0.x = fmaf(w, x0.x, a0.x); a0.y = fmaf(w, x0.y, a0.y);
        a0.z = fmaf(w, x0.z, a0.z); a0.w = fmaf(w, x0.w, a0.w);
        a1.x = fmaf(w, x1.x, a1.x); a1.y = fmaf(w, x1.y, a1.y);
        a1.z = fmaf(w, x1.z, a1.z); a1.w = fmaf(w, x1.w, a1.w);
        sw += w;
    }
#pragma unroll
    for (int m = 16; m <= 32; m <<= 1) {
        a0.x += __shfl_xor(a0.x, m); a0.y += __shfl_xor(a0.y, m);
        a0.z += __shfl_xor(a0.z, m); a0.w += __shfl_xor(a0.w, m);
        a1.x += __shfl_xor(a1.x, m); a1.y += __shfl_xor(a1.y, m);
        a1.z += __shfl_xor(a1.z, m); a1.w += __shfl_xor(a1.w, m);
        sw   += __shfl_xor(sw, m);
    }
    float inv = 1.0f / fmaxf(sw, 1e-6f);
    if (slot == 0) {
        a0.x *= inv; a0.y *= inv; a0.z *= inv; a0.w *= inv;
        a1.x *= inv; a1.y *= inv; a1.z *= inv; a1.w *= inv;
        *reinterpret_cast<float4*>(dstp + l4 * 4) = a0;
        *reinterpret_cast<float4*>(dstp + 64 + l4 * 4) = a1;
    }
}

// ---------------------------------------------------------------- fused K2+K3
// block = 256 thr = 4 waves; wave owns 32 rows.  K2: acc[2][8] over K=256
// (agg@Wl then xC@Wc), A fp32 global->reg + in-reg split; B frag-order
// coalesced 1KB loads.  Epilogue -> per-wave 16KB LDS slice -> K3 -> out.
__global__ __launch_bounds__(256) void k_fused(
    const float* __restrict__ xC, const float* __restrict__ aggn,
    const int* __restrict__ cnt,
    const u16* __restrict__ wlh, const u16* __restrict__ wll,
    const u16* __restrict__ wch, const u16* __restrict__ wcl,
    const u16* __restrict__ woh, const u16* __restrict__ wol,
    const float* __restrict__ bc, const float* __restrict__ lng,
    const float* __restrict__ lnb, const float* __restrict__ bout,
    float* __restrict__ out, int N)
{
    __shared__ float lds[4 * 32 * 128];     // 64 KB, per-wave 16KB slices

    const int lane = threadIdx.x & 63;
    const int wid  = threadIdx.x >> 6;
    const int lr   = lane & 15;        // frag row (A) / col (B/C)
    const int kb   = lane >> 4;        // k-block 0..3
    const int row0 = blockIdx.x * 128 + wid * 32;
    float* myl = lds + wid * 32 * 128;

    // ================= K2 =================
    v4f acc[2][8] = {};

#pragma unroll
    for (int mat = 0; mat < 2; ++mat) {
        const float* Asrc = mat ? xC : aggn;
        const uint4* BH = (const uint4*)(mat ? wch : wlh);
        const uint4* BL = (const uint4*)(mat ? wcl : wll);
#pragma unroll
        for (int kc = 0; kc < 4; ++kc) {
            Frag ah[2], al[2];
#pragma unroll
            for (int rt = 0; rt < 2; ++rt) {
                int r = row0 + rt * 16 + lr;
                r = (r < N) ? r : (N - 1);
                const float4* ap = (const float4*)(
                    Asrc + (size_t)r * HD + kc * 32 + kb * 8);
                float4 u0 = ap[0], u1 = ap[1];
                float f[8] = {u0.x, u0.y, u0.z, u0.w, u1.x, u1.y, u1.z, u1.w};
                cvt_split8(f, ah[rt].u, al[rt].u);
            }
#pragma unroll
            for (int ct = 0; ct < 8; ++ct) {
                int idx = (kc * 8 + ct) * 64 + lane;   // coalesced 1KB
                Frag bh, bl;
                bh.q = BH[idx];
                bl.q = BL[idx];
#pragma unroll
                for (int rt = 0; rt < 2; ++rt) {
                    acc[rt][ct] = __builtin_amdgcn_mfma_f32_16x16x32_bf16(
                        ah[rt].v, bh.v, acc[rt][ct], 0, 0, 0);
                    acc[rt][ct] = __builtin_amdgcn_mfma_f32_16x16x32_bf16(
                        ah[rt].v, bl.v, acc[rt][ct], 0, 0, 0);
                    acc[rt][ct] = __builtin_amdgcn_mfma_f32_16x16x32_bf16(
                        al[rt].v, bh.v, acc[rt][ct], 0, 0, 0);
                }
            }
        }
    }

    // ---- epilogue: bias, relu, LN (shfl over 16-lane group), select -> LDS
    float bcv[8], gav[8], bev[8];
#pragma unroll
    for (int ct = 0; ct < 8; ++ct) {
        int c = ct * 16 + lr;
        bcv[ct] = bc[c];
        gav[ct] = lng[c];
        bev[ct] = lnb[c];
    }

#pragma unroll
    for (int rt = 0; rt < 2; ++rt) {
        int rq = row0 + rt * 16 + kb * 4;    // first of this lane's 4 rows
        int cvr[4] = {0, 0, 0, 0};
        if (rq < N) {                        // N%4==0, rq%4==0 -> rq+3 < N
            int4 cv = *(const int4*)(cnt + rq);
            cvr[0] = cv.x; cvr[1] = cv.y; cvr[2] = cv.z; cvr[3] = cv.w;
        }
#pragma unroll
        for (int reg = 0; reg < 4; ++reg) {
            int rloc = rt * 16 + kb * 4 + reg;
            int r    = rq + reg;
            float yv[8];
            float s = 0.f, q = 0.f;
#pragma unroll
            for (int ct = 0; ct < 8; ++ct) {
                float v = acc[rt][ct][reg] + bcv[ct];
                v = fmaxf(v, 0.0f);
                yv[ct] = v;
                s += v;
                q += v * v;
            }
#pragma unroll
            for (int m = 1; m < 16; m <<= 1) {
                s += __shfl_xor(s, m);
                q += __shfl_xor(q, m);
            }
            float mu   = s * (1.0f / 128.0f);
            float var  = q * (1.0f / 128.0f) - mu * mu;
            float rstd = rsqrtf(var + 1e-5f);

            if (r < N) {
                if (cvr[reg] > 0) {
#pragma unroll
                    for (int ct = 0; ct < 8; ++ct)
                        myl[swz(rloc, ct * 16 + lr)] =
                            (yv[ct] - mu) * rstd * gav[ct] + bev[ct];
                } else {
                    size_t base = (size_t)r * HD;
#pragma unroll
                    for (int ct = 0; ct < 8; ++ct)
                        myl[swz(rloc, ct * 16 + lr)] = xC[base + ct * 16 + lr];
                }
            } else {
#pragma unroll
                for (int ct = 0; ct < 8; ++ct)
                    myl[swz(rloc, ct * 16 + lr)] = 0.0f;
            }
        }
    }

    __syncthreads();   // order LDS writes before K3 reads (wave-local, but safe)

    // ================= K3 =================
    v4f acc2[2][4] = {};
    const uint4* BH3 = (const uint4*)woh;
    const uint4* BL3 = (const uint4*)wol;

#pragma unroll
    for (int kc = 0; kc < 4; ++kc) {
        Frag ah[2], al[2];
#pragma unroll
        for (int rt = 0; rt < 2; ++rt) {
            int rloc = rt * 16 + lr;
            int c0   = kc * 32 + kb * 8;
            float4 u0 = *reinterpret_cast<const float4*>(&myl[swz(rloc, c0)]);
            float4 u1 = *reinterpret_cast<const float4*>(&myl[swz(rloc, c0 + 4)]);
            float f[8] = {u0.x, u0.y, u0.z, u0.w, u1.x, u1.y, u1.z, u1.w};
            cvt_split8(f, ah[rt].u, al[rt].u);
        }
#pragma unroll
        for (int ct = 0; ct < 4; ++ct) {
            int idx = (kc * 4 + ct) * 64 + lane;   // coalesced 1KB
            Frag bh, bl;
            bh.q = BH3[idx];
            bl.q = BL3[idx];
#pragma unroll
            for (int rt = 0; rt < 2; ++rt) {
                acc2[rt][ct] = __builtin_amdgcn_mfma_f32_16x16x32_bf16(
                    ah[rt].v, bh.v, acc2[rt][ct], 0, 0, 0);
                acc2[rt][ct] = __builtin_amdgcn_mfma_f32_16x16x32_bf16(
                    ah[rt].v, bl.v, acc2[rt][ct], 0, 0, 0);
                acc2[rt][ct] = __builtin_amdgcn_mfma_f32_16x16x32_bf16(
                    al[rt].v, bh.v, acc2[rt][ct], 0, 0, 0);
            }
        }
    }

    float bov[4];
#pragma unroll
    for (int ct = 0; ct < 4; ++ct) bov[ct] = bout[ct * 16 + lr];

#pragma unroll
    for (int rt = 0; rt < 2; ++rt) {
#pragma unroll
        for (int reg = 0; reg < 4; ++reg) {
            int r = row0 + rt * 16 + kb * 4 + reg;
            if (r < N) {
#pragma unroll
                for (int ct = 0; ct < 4; ++ct)
                    out[(size_t)r * OD + ct * 16 + lr] =
                        acc2[rt][ct][reg] + bov[ct];
            }
        }
    }
}

// ---------------------------------------------------------------- launch
extern "C" void kernel_launch(void* const* d_in, const int* in_sizes, int n_in,
                              void* d_out, int out_size, void* d_ws, size_t ws_size,
                              hipStream_t stream) {
    const float* xB    = (const float*)d_in[1];
    const float* xC    = (const float*)d_in[2];
    const float* tB    = (const float*)d_in[4];
    const float* tC    = (const float*)d_in[5];
    const int*   edge2 = (const int*)d_in[7];
    const float* Wl1   = (const float*)d_in[18];
    const float* bl1   = (const float*)d_in[19];
    const float* W01   = (const float*)d_in[20];
    const float* b01   = (const float*)d_in[21];
    const float* W11   = (const float*)d_in[22];
    const float* b11   = (const float*)d_in[23];
    const float* gate1 = (const float*)d_in[24];
    const float* lam1  = (const float*)d_in[25];
    const float* lng1  = (const float*)d_in[26];
    const float* lnb1  = (const float*)d_in[27];
    const float* Wout  = (const float*)d_in[28];
    const float* bout  = (const float*)d_in[29];

    const int N = in_sizes[2] / HD;
    const int E = in_sizes[7] / 2;

    int*   cnt   = (int*)d_ws;
    int*   fillc = cnt + N;
    int*   offs  = fillc + N;
    int*   part  = offs + N;
    int*   tot   = part + 128;
    int2*  srcw  = (int2*)(tot + 4);
    u16*   wlh   = (u16*)(srcw + E);
    u16*   wll   = wlh + 16384;
    u16*   wch   = wll + 16384;
    u16*   wcl   = wch + 16384;
    u16*   woh   = wcl + 16384;
    u16*   wol   = woh + 8192;
    float* bc    = (float*)(wol + 8192);
    float* buf   = bc + 128;             // agg_norm fp32

    hipMemsetAsync(cnt, 0, (size_t)2 * N * sizeof(int), stream);
    hipMemsetAsync(tot, 0, sizeof(int), stream);

    dim3 blk(256);
    const int gE = (E + 255) / 256;
    const int NB = (N + SCAN_E - 1) / SCAN_E;

    k_prep <<<gE + 97, blk, 0, stream>>>(edge2, cnt, E, gE,
                                         Wl1, W01, W11, Wout, bl1, b01, b11,
                                         gate1, wlh, wll, wch, wcl, woh, wol, bc);
    k_scan1<<<NB, blk, 0, stream>>>(cnt, offs, part, tot, N);
    k_fillw<<<gE, blk, 0, stream>>>(edge2, tB, tC, lam1, offs, part, fillc, srcw, E);

    const int gN64 = (N * 64 + 255) / 256;
    k_gather<<<gN64, blk, 0, stream>>>(xB, srcw, offs, part, cnt, buf, N);

    const int GB = (N + 127) / 128;
    k_fused<<<GB, blk, 0, stream>>>(xC, buf, cnt, wlh, wll, wch, wcl, woh, wol,
                                    bc, lng1, lnb1, bout, (float*)d_out, N);
}